// Round 4
// baseline (394.797 us; speedup 1.0000x reference)
//
#include <hip/hip_runtime.h>

typedef __attribute__((ext_vector_type(8))) short bf16x8;
typedef __attribute__((ext_vector_type(4))) float f32x4;

#define HH 768   // hidden
#define EE 768   // embed
#define BB 32
#define SS 512
#define PP 76
#define KCAND 64
#define MM (BB * PP)   // 2432
#define VV 50257
#define NC (MM * KCAND)  // 155648

// ws byte offsets (all 16B-aligned where vector-accessed)
#define OFF_WT     0u          // bf16 768*768      = 1,179,648
#define OFF_AG     1183744u    // bf16 2432*768     = 3,735,552
#define OFF_LMRAW  4923392u    // fp32 2432*768     = 7,471,104
#define OFF_LMN    12394496u   // bf16 2432*768     = 3,735,552
#define OFF_COUNT  16130048u   // int  50257        = 201,028
#define OFF_CURSOR (OFF_COUNT + 201028u)   // int 50257 (contiguous w/ COUNT for one zero pass)
#define OFF_BASE   (OFF_CURSOR + 201028u)  // int 50257
#define OFF_PERM   (OFF_BASE + 201028u)    // int 155648

#define WT_BLOCKS 576
#define AG_BLOCKS 304
#define HIST_BLOCKS 152   // 152*256*4 = 155,648

__device__ inline unsigned short f2bf(float f) {
    unsigned int u = __float_as_uint(f);
    u += 0x7fffu + ((u >> 16) & 1u);
    return (unsigned short)(u >> 16);
}
__device__ inline float bf2f(unsigned short h) {
    return __uint_as_float(((unsigned int)h) << 16);
}

// zero count+cursor (ws is poisoned 0xAA every call)
__global__ __launch_bounds__(256) void zero_kernel(int* p) {
    const int i = blockIdx.x * 256 + threadIdx.x;
    if (i < 2 * VV) p[i] = 0;
}

// Pass 0 (one dispatch): W transpose+convert -> Wt[e][h] bf16 ;
// gather masked rows -> Ag[m][k] bf16 ; histogram of candidate row ids.
__global__ __launch_bounds__(256) void prep_kernel(
    const float* __restrict__ W, unsigned short* __restrict__ Wt,
    const float* __restrict__ seq, const int* __restrict__ mpos,
    unsigned short* __restrict__ Ag,
    const int* __restrict__ cand, int* __restrict__ count) {
    const int bid = blockIdx.x;
    if (bid < WT_BLOCKS) {
        __shared__ float tile[32][33];
        const int h0 = (bid % 24) * 32, e0 = (bid / 24) * 32;
        const int c = threadIdx.x & 31, r = threadIdx.x >> 5;
#pragma unroll
        for (int rr = r; rr < 32; rr += 8)
            tile[rr][c] = W[(size_t)(h0 + rr) * EE + e0 + c];
        __syncthreads();
#pragma unroll
        for (int rr = r; rr < 32; rr += 8)
            Wt[(size_t)(e0 + rr) * HH + h0 + c] = f2bf(tile[c][rr]);
    } else if (bid < WT_BLOCKS + AG_BLOCKS) {
        const int m0 = (bid - WT_BLOCKS) * 8;
        const int t = threadIdx.x;
#pragma unroll
        for (int rr = 0; rr < 8; ++rr) {
            const int m = m0 + rr;
            const int b = m / PP, p = m - b * PP;
            const int ps = mpos[b * PP + p];
            const float* srow = seq + (size_t)(b * SS + ps) * HH;
            unsigned short* drow = Ag + (size_t)m * HH;
#pragma unroll
            for (int j = 0; j < 3; ++j)
                drow[t + j * 256] = f2bf(srow[t + j * 256]);
        }
    } else {
        const int h = bid - WT_BLOCKS - AG_BLOCKS;
        const int i0 = (h * 256 + threadIdx.x) * 4;
#pragma unroll
        for (int j = 0; j < 4; ++j)
            atomicAdd(&count[cand[i0 + j]], 1);
    }
}

// Exclusive scan of count[0..VV) -> base[], cursor[] (single block, 1024 thr)
__global__ __launch_bounds__(1024) void scan_kernel(
    const int* __restrict__ count, int* __restrict__ base, int* __restrict__ cursor) {
    __shared__ int part[1024];
    const int t = threadIdx.x;
    const int lo = t * 50, hi = (lo + 50 < VV) ? lo + 50 : VV;
    int s = 0;
    for (int i = lo; i < hi; ++i) s += count[i];
    part[t] = s;
    __syncthreads();
    for (int off = 1; off < 1024; off <<= 1) {
        const int v = (t >= off) ? part[t - off] : 0;
        __syncthreads();
        part[t] += v;
        __syncthreads();
    }
    int run = part[t] - s;  // exclusive prefix at chunk start
    for (int i = lo; i < hi; ++i) {
        base[i] = run; cursor[i] = run;
        run += count[i];
    }
}

// Scatter candidate occurrences into row-grouped perm[]
__global__ __launch_bounds__(256) void scatter_kernel(
    const int* __restrict__ cand, int* __restrict__ cursor, int* __restrict__ perm) {
    const int i = blockIdx.x * 256 + threadIdx.x;  // grid covers NC exactly
    const int row = cand[i];
    const int slot = atomicAdd(&cursor[row], 1);
    perm[slot] = i;
}

// Pass 1: lm_raw[m][e] = sum_h Ag[m][h] * Wt[e][h]  (bf16 MFMA, 64x64, BK=128)
__global__ __launch_bounds__(256) void gemm_kernel(
    const unsigned short* __restrict__ Ag, const unsigned short* __restrict__ Wt,
    float* __restrict__ lm) {
    __shared__ unsigned short Alds[64][136];
    __shared__ unsigned short Blds[64][136];
    const int bm = blockIdx.y, bn = blockIdx.x;
    const int tid = threadIdx.x;
    const int sr = tid >> 4;
    const int sc = (tid & 15) * 8;
    const unsigned short* abase = Ag + (size_t)(bm * 64) * HH;
    const unsigned short* bbase = Wt + (size_t)(bn * 64) * HH;

    const int lane = tid & 63, wv = tid >> 6;
    const int wm = wv >> 1, wn = wv & 1;
    const int fr = lane & 15, fq = (lane >> 4) * 8;
    f32x4 acc[2][2] = {};

    for (int kk = 0; kk < HH; kk += 128) {
        __syncthreads();
#pragma unroll
        for (int rnd = 0; rnd < 4; ++rnd) {
            const int row = sr + rnd * 16;
            *(int4*)&Alds[row][sc] = *(const int4*)(abase + (size_t)row * HH + kk + sc);
            *(int4*)&Blds[row][sc] = *(const int4*)(bbase + (size_t)row * HH + kk + sc);
        }
        __syncthreads();
#pragma unroll
        for (int ks = 0; ks < 128; ks += 32) {
            bf16x8 af[2], bfr[2];
#pragma unroll
            for (int t = 0; t < 2; ++t)
                af[t] = *(const bf16x8*)&Alds[wm * 32 + t * 16 + fr][ks + fq];
#pragma unroll
            for (int t = 0; t < 2; ++t)
                bfr[t] = *(const bf16x8*)&Blds[wn * 32 + t * 16 + fr][ks + fq];
#pragma unroll
            for (int tm = 0; tm < 2; ++tm)
#pragma unroll
                for (int tn = 0; tn < 2; ++tn)
                    acc[tm][tn] = __builtin_amdgcn_mfma_f32_16x16x32_bf16(
                        af[tm], bfr[tn], acc[tm][tn], 0, 0, 0);
        }
    }
#pragma unroll
    for (int tm = 0; tm < 2; ++tm)
#pragma unroll
        for (int tn = 0; tn < 2; ++tn) {
            const int col = bn * 64 + wn * 32 + tn * 16 + (lane & 15);
            const int rbase = bm * 64 + wm * 32 + tm * 16 + (lane >> 4) * 4;
#pragma unroll
            for (int g = 0; g < 4; ++g)
                lm[(size_t)(rbase + g) * EE + col] = acc[tm][tn][g];
        }
}

// Pass 2: bias + LayerNorm, write bf16 lm_n (3.7 MB -> L2-resident).
// One wave per row; lane owns elems [lane*8, lane*8+8) and [512+lane*4, +4).
__global__ __launch_bounds__(256) void ln_kernel(
    const float* __restrict__ lm, const float* __restrict__ bias,
    const float* __restrict__ gamma, const float* __restrict__ beta,
    unsigned short* __restrict__ lmn) {
    const int lane = threadIdx.x & 63;
    const int m = blockIdx.x * 4 + (threadIdx.x >> 6);
    const float4* x4 = (const float4*)(lm + (size_t)m * EE);
    const float4* b4 = (const float4*)bias;
    const float4* g4 = (const float4*)gamma;
    const float4* e4 = (const float4*)beta;
    float x[12], g[12], e[12];
    {
        const float4 X0 = x4[lane * 2], X1 = x4[lane * 2 + 1], X2 = x4[128 + lane];
        const float4 B0 = b4[lane * 2], B1 = b4[lane * 2 + 1], B2 = b4[128 + lane];
        const float4 G0 = g4[lane * 2], G1 = g4[lane * 2 + 1], G2 = g4[128 + lane];
        const float4 E0 = e4[lane * 2], E1 = e4[lane * 2 + 1], E2 = e4[128 + lane];
        x[0]=X0.x+B0.x; x[1]=X0.y+B0.y; x[2]=X0.z+B0.z; x[3]=X0.w+B0.w;
        x[4]=X1.x+B1.x; x[5]=X1.y+B1.y; x[6]=X1.z+B1.z; x[7]=X1.w+B1.w;
        x[8]=X2.x+B2.x; x[9]=X2.y+B2.y; x[10]=X2.z+B2.z; x[11]=X2.w+B2.w;
        g[0]=G0.x; g[1]=G0.y; g[2]=G0.z; g[3]=G0.w;
        g[4]=G1.x; g[5]=G1.y; g[6]=G1.z; g[7]=G1.w;
        g[8]=G2.x; g[9]=G2.y; g[10]=G2.z; g[11]=G2.w;
        e[0]=E0.x; e[1]=E0.y; e[2]=E0.z; e[3]=E0.w;
        e[4]=E1.x; e[5]=E1.y; e[6]=E1.z; e[7]=E1.w;
        e[8]=E2.x; e[9]=E2.y; e[10]=E2.z; e[11]=E2.w;
    }
    float s = 0.f, q = 0.f;
#pragma unroll
    for (int i = 0; i < 12; ++i) { s += x[i]; q += x[i] * x[i]; }
#pragma unroll
    for (int m2 = 32; m2; m2 >>= 1) { s += __shfl_xor(s, m2); q += __shfl_xor(q, m2); }
    const float mu = s * (1.0f / 768.0f);
    const float rstd = rsqrtf(q * (1.0f / 768.0f) - mu * mu + 1e-12f);
    unsigned short o8[8];
#pragma unroll
    for (int i = 0; i < 8; ++i) o8[i] = f2bf((x[i] - mu) * rstd * g[i] + e[i]);
    *(int4*)(lmn + (size_t)m * EE + lane * 8) = *(const int4*)o8;
    unsigned short o4[4];
#pragma unroll
    for (int i = 0; i < 4; ++i) o4[i] = f2bf((x[8 + i] - mu) * rstd * g[8 + i] + e[8 + i]);
    *(ushort2*)(lmn + (size_t)m * EE + 512 + lane * 4) = *(const ushort2*)o4;      // low half
    *(ushort2*)(lmn + (size_t)m * EE + 512 + lane * 4 + 2) = *(const ushort2*)(o4 + 2);
}

// Pass 3: one wave per unique embedding row. Load emb row fp32 once,
// dot against each occurrence's L2-resident bf16 lm_n row.
__global__ __launch_bounds__(256) void group_logits_kernel(
    const float* __restrict__ emb, const unsigned short* __restrict__ lmn,
    const int* __restrict__ count, const int* __restrict__ basep,
    const int* __restrict__ perm, float* __restrict__ out) {
    const int lane = threadIdx.x & 63;
    const int r = blockIdx.x * 4 + (threadIdx.x >> 6);
    if (r >= VV) return;
    const int c = count[r];
    if (c == 0) return;
    const int base = basep[r];
    const float4* e4 = (const float4*)(emb + (size_t)r * EE);
    const float4 E0 = e4[lane * 2], E1 = e4[lane * 2 + 1], E2 = e4[128 + lane];
    const int l8 = lane * 8, l4 = 512 + lane * 4;

    for (int o = 0; o < c; o += 4) {
        const int nn = c - o;  // wave-uniform
        int idxv[4]; bf16x8 c8[4]; ushort4 c4v[4];
#pragma unroll
        for (int j = 0; j < 4; ++j) {
            const int jj = (j < nn) ? j : 0;
            const int idx = perm[base + o + jj];
            idxv[j] = idx;
            const unsigned short* lrow = lmn + (size_t)(idx >> 6) * EE;
            c8[j] = *(const bf16x8*)(lrow + l8);
            c4v[j] = *(const ushort4*)(lrow + l4);
        }
        float d[4];
#pragma unroll
        for (int j = 0; j < 4; ++j) {
            d[j] = bf2f((unsigned short)c8[j][0]) * E0.x
                 + bf2f((unsigned short)c8[j][1]) * E0.y
                 + bf2f((unsigned short)c8[j][2]) * E0.z
                 + bf2f((unsigned short)c8[j][3]) * E0.w
                 + bf2f((unsigned short)c8[j][4]) * E1.x
                 + bf2f((unsigned short)c8[j][5]) * E1.y
                 + bf2f((unsigned short)c8[j][6]) * E1.z
                 + bf2f((unsigned short)c8[j][7]) * E1.w
                 + bf2f(c4v[j].x) * E2.x + bf2f(c4v[j].y) * E2.y
                 + bf2f(c4v[j].z) * E2.z + bf2f(c4v[j].w) * E2.w;
        }
#pragma unroll
        for (int m2 = 32; m2; m2 >>= 1) {
#pragma unroll
            for (int j = 0; j < 4; ++j) d[j] += __shfl_xor(d[j], m2);
        }
        if (lane == 0) {
#pragma unroll
            for (int j = 0; j < 4; ++j)
                if (j < nn) out[idxv[j]] = d[j];
        }
    }
}

extern "C" void kernel_launch(void* const* d_in, const int* in_sizes, int n_in,
                              void* d_out, int out_size, void* d_ws, size_t ws_size,
                              hipStream_t stream) {
    const float* seq   = (const float*)d_in[0];
    const int*   mpos  = (const int*)d_in[1];
    const int*   cand  = (const int*)d_in[2];
    const float* emb   = (const float*)d_in[3];
    const float* W     = (const float*)d_in[4];
    const float* bias  = (const float*)d_in[5];
    const float* gamma = (const float*)d_in[6];
    const float* beta  = (const float*)d_in[7];
    float* out = (float*)d_out;

    char* ws = (char*)d_ws;
    unsigned short* Wt   = (unsigned short*)(ws + OFF_WT);
    unsigned short* Ag   = (unsigned short*)(ws + OFF_AG);
    float*          lm   = (float*)(ws + OFF_LMRAW);
    unsigned short* lmn  = (unsigned short*)(ws + OFF_LMN);
    int*            cnt  = (int*)(ws + OFF_COUNT);
    int*            cur  = (int*)(ws + OFF_CURSOR);
    int*            bse  = (int*)(ws + OFF_BASE);
    int*            perm = (int*)(ws + OFF_PERM);

    zero_kernel<<<(2 * VV + 255) / 256, 256, 0, stream>>>(cnt);  // cnt+cur contiguous
    prep_kernel<<<WT_BLOCKS + AG_BLOCKS + HIST_BLOCKS, 256, 0, stream>>>(
        W, Wt, seq, mpos, Ag, cand, cnt);
    scan_kernel<<<1, 1024, 0, stream>>>(cnt, bse, cur);
    scatter_kernel<<<NC / 256, 256, 0, stream>>>(cand, cur, perm);
    gemm_kernel<<<dim3(12, 38), 256, 0, stream>>>(Ag, Wt, lm);
    ln_kernel<<<MM / 4, 256, 0, stream>>>(lm, bias, gamma, beta, lmn);
    group_logits_kernel<<<(VV + 3) / 4, 256, 0, stream>>>(emb, lmn, cnt, bse, perm, out);
}

// Round 5
// 281.055 us; speedup vs baseline: 1.4047x; 1.4047x over previous
//
#include <hip/hip_runtime.h>

typedef __attribute__((ext_vector_type(8))) short bf16x8;
typedef __attribute__((ext_vector_type(4))) float f32x4;

#define HH 768
#define EE 768
#define BB 32
#define SS 512
#define PP 76
#define KCAND 64
#define MM (BB * PP)     // 2432
#define VV 50257
#define NC (MM * KCAND)  // 155648
#define CAP 16           // bucket capacity per row; spill -> overflow list
#define OVF_CAP 4096

// ws byte offsets (16B aligned)
#define OFF_WT    0u          // bf16 768*768   = 1,179,648
#define OFF_AG    1179648u    // bf16 2432*768  = 3,735,552
#define OFF_LM    4915200u    // fp32 2432*768  = 7,471,104
#define OFF_LMN   12386304u   // bf16 2432*768  = 3,735,552
#define OFF_CUR   16121856u   // int  50257+1 (last = overflow counter)
#define OFF_PERM2 16322896u   // int  50257*16 = 3,216,448
#define OFF_OVF   19539344u   // int  4096

#define WT_BLOCKS 576
#define AG_BLOCKS 304
#define ZR_BLOCKS 197        // (50258+255)/256
#define GEMM_BLOCKS 456      // 12 x 38
#define SC_BLOCKS 608        // 608*256 == NC
#define ROW_BLOCKS 12565     // ceil(VV/4), 4 waves/block, wave per row
#define OVF_BLOCKS 32

__device__ inline unsigned short f2bf(float f) {
    unsigned int u = __float_as_uint(f);
    u += 0x7fffu + ((u >> 16) & 1u);
    return (unsigned short)(u >> 16);
}
__device__ inline float bf2f(unsigned short h) {
    return __uint_as_float(((unsigned int)h) << 16);
}

// L1: W transpose+convert -> Wt[e][h] ; gather masked rows -> Ag[m][k] ;
// zero cursor[0..VV] (cursor[VV] is the overflow counter).
__global__ __launch_bounds__(256) void prep_kernel(
    const float* __restrict__ W, unsigned short* __restrict__ Wt,
    const float* __restrict__ seq, const int* __restrict__ mpos,
    unsigned short* __restrict__ Ag, int* __restrict__ cursor) {
    const int bid = blockIdx.x;
    if (bid < WT_BLOCKS) {
        __shared__ float tile[32][33];
        const int h0 = (bid % 24) * 32, e0 = (bid / 24) * 32;
        const int c = threadIdx.x & 31, r = threadIdx.x >> 5;
#pragma unroll
        for (int rr = r; rr < 32; rr += 8)
            tile[rr][c] = W[(size_t)(h0 + rr) * EE + e0 + c];
        __syncthreads();
#pragma unroll
        for (int rr = r; rr < 32; rr += 8)
            Wt[(size_t)(e0 + rr) * HH + h0 + c] = f2bf(tile[c][rr]);
    } else if (bid < WT_BLOCKS + AG_BLOCKS) {
        const int m0 = (bid - WT_BLOCKS) * 8;
        const int t = threadIdx.x;
#pragma unroll
        for (int rr = 0; rr < 8; ++rr) {
            const int m = m0 + rr;
            const int b = m / PP, p = m - b * PP;
            const int ps = mpos[b * PP + p];
            const float* srow = seq + (size_t)(b * SS + ps) * HH;
            unsigned short* drow = Ag + (size_t)m * HH;
#pragma unroll
            for (int j = 0; j < 3; ++j)
                drow[t + j * 256] = f2bf(srow[t + j * 256]);
        }
    } else {
        const int i = (bid - WT_BLOCKS - AG_BLOCKS) * 256 + threadIdx.x;
        if (i <= VV) cursor[i] = 0;
    }
}

// L2: bf16 MFMA GEMM (64x64 tile, BK=64) + bucket scatter.
__global__ __launch_bounds__(256) void gemm_scatter_kernel(
    const unsigned short* __restrict__ Ag, const unsigned short* __restrict__ Wt,
    float* __restrict__ lm, const int* __restrict__ cand,
    int* __restrict__ cursor, int* __restrict__ perm2, int* __restrict__ ovf) {
    const int bid = blockIdx.x;
    if (bid < GEMM_BLOCKS) {
        __shared__ unsigned short Alds[64][72];
        __shared__ unsigned short Blds[64][72];
        const int bn = bid % 12, bm = bid / 12;
        const int tid = threadIdx.x;
        const int sr = tid >> 2, sc = (tid & 3) * 16;
        const unsigned short* abase = Ag + (size_t)(bm * 64) * HH;
        const unsigned short* bbase = Wt + (size_t)(bn * 64) * HH;
        const int lane = tid & 63, wv = tid >> 6;
        const int wm = wv >> 1, wn = wv & 1;
        const int fr = lane & 15, fq = (lane >> 4) * 8;
        f32x4 acc[2][2] = {};
        for (int kk = 0; kk < HH; kk += 64) {
            __syncthreads();
            *(int4*)&Alds[sr][sc]     = *(const int4*)(abase + (size_t)sr * HH + kk + sc);
            *(int4*)&Alds[sr][sc + 8] = *(const int4*)(abase + (size_t)sr * HH + kk + sc + 8);
            *(int4*)&Blds[sr][sc]     = *(const int4*)(bbase + (size_t)sr * HH + kk + sc);
            *(int4*)&Blds[sr][sc + 8] = *(const int4*)(bbase + (size_t)sr * HH + kk + sc + 8);
            __syncthreads();
#pragma unroll
            for (int ks = 0; ks < 64; ks += 32) {
                bf16x8 af[2], bfr[2];
#pragma unroll
                for (int t = 0; t < 2; ++t)
                    af[t] = *(const bf16x8*)&Alds[wm * 32 + t * 16 + fr][ks + fq];
#pragma unroll
                for (int t = 0; t < 2; ++t)
                    bfr[t] = *(const bf16x8*)&Blds[wn * 32 + t * 16 + fr][ks + fq];
#pragma unroll
                for (int tm = 0; tm < 2; ++tm)
#pragma unroll
                    for (int tn = 0; tn < 2; ++tn)
                        acc[tm][tn] = __builtin_amdgcn_mfma_f32_16x16x32_bf16(
                            af[tm], bfr[tn], acc[tm][tn], 0, 0, 0);
            }
        }
#pragma unroll
        for (int tm = 0; tm < 2; ++tm)
#pragma unroll
            for (int tn = 0; tn < 2; ++tn) {
                const int col = bn * 64 + wn * 32 + tn * 16 + (lane & 15);
                const int rbase = bm * 64 + wm * 32 + tm * 16 + (lane >> 4) * 4;
#pragma unroll
                for (int g = 0; g < 4; ++g)
                    lm[(size_t)(rbase + g) * EE + col] = acc[tm][tn][g];
            }
    } else {
        const int i = (bid - GEMM_BLOCKS) * 256 + threadIdx.x;  // covers NC exactly
        const int row = cand[i];
        const int slot = atomicAdd(&cursor[row], 1);
        if (slot < CAP) {
            perm2[row * CAP + slot] = i;
        } else {
            const int j = atomicAdd(&cursor[VV], 1);
            if (j < OVF_CAP) ovf[j] = i;
        }
    }
}

// L3: bias + LayerNorm, write bf16 lmn (3.7 MB -> L2-resident).
__global__ __launch_bounds__(256) void ln_kernel(
    const float* __restrict__ lm, const float* __restrict__ bias,
    const float* __restrict__ gamma, const float* __restrict__ beta,
    unsigned short* __restrict__ lmn) {
    const int lane = threadIdx.x & 63;
    const int m = blockIdx.x * 4 + (threadIdx.x >> 6);
    const float4* x4 = (const float4*)(lm + (size_t)m * EE);
    const float4* b4 = (const float4*)bias;
    const float4* g4 = (const float4*)gamma;
    const float4* e4 = (const float4*)beta;
    float x[12], g[12], e[12];
    {
        const float4 X0 = x4[lane * 2], X1 = x4[lane * 2 + 1], X2 = x4[128 + lane];
        const float4 B0 = b4[lane * 2], B1 = b4[lane * 2 + 1], B2 = b4[128 + lane];
        const float4 G0 = g4[lane * 2], G1 = g4[lane * 2 + 1], G2 = g4[128 + lane];
        const float4 E0 = e4[lane * 2], E1 = e4[lane * 2 + 1], E2 = e4[128 + lane];
        x[0]=X0.x+B0.x; x[1]=X0.y+B0.y; x[2]=X0.z+B0.z; x[3]=X0.w+B0.w;
        x[4]=X1.x+B1.x; x[5]=X1.y+B1.y; x[6]=X1.z+B1.z; x[7]=X1.w+B1.w;
        x[8]=X2.x+B2.x; x[9]=X2.y+B2.y; x[10]=X2.z+B2.z; x[11]=X2.w+B2.w;
        g[0]=G0.x; g[1]=G0.y; g[2]=G0.z; g[3]=G0.w;
        g[4]=G1.x; g[5]=G1.y; g[6]=G1.z; g[7]=G1.w;
        g[8]=G2.x; g[9]=G2.y; g[10]=G2.z; g[11]=G2.w;
        e[0]=E0.x; e[1]=E0.y; e[2]=E0.z; e[3]=E0.w;
        e[4]=E1.x; e[5]=E1.y; e[6]=E1.z; e[7]=E1.w;
        e[8]=E2.x; e[9]=E2.y; e[10]=E2.z; e[11]=E2.w;
    }
    float s = 0.f, q = 0.f;
#pragma unroll
    for (int i = 0; i < 12; ++i) { s += x[i]; q += x[i] * x[i]; }
#pragma unroll
    for (int m2 = 32; m2; m2 >>= 1) { s += __shfl_xor(s, m2); q += __shfl_xor(q, m2); }
    const float mu = s * (1.0f / 768.0f);
    const float rstd = rsqrtf(q * (1.0f / 768.0f) - mu * mu + 1e-12f);
    unsigned short o8[8];
#pragma unroll
    for (int i = 0; i < 8; ++i) o8[i] = f2bf((x[i] - mu) * rstd * g[i] + e[i]);
    *(int4*)(lmn + (size_t)m * EE + lane * 8) = *(const int4*)o8;
    unsigned short o4[4];
#pragma unroll
    for (int i = 0; i < 4; ++i) o4[i] = f2bf((x[8 + i] - mu) * rstd * g[8 + i] + e[8 + i]);
    *(ushort2*)(lmn + (size_t)m * EE + 512 + lane * 4) = *(const ushort2*)o4;
    *(ushort2*)(lmn + (size_t)m * EE + 512 + lane * 4 + 2) = *(const ushort2*)(o4 + 2);
}

// L4: one wave per unique row (emb row fetched once, compulsory traffic only),
// dots vs L2-resident bf16 lmn rows. Tail blocks drain the overflow list.
__global__ __launch_bounds__(256) void group_logits_kernel(
    const float* __restrict__ emb, const unsigned short* __restrict__ lmn,
    const int* __restrict__ cursor, const int* __restrict__ perm2,
    const int* __restrict__ ovf, const int* __restrict__ cand,
    float* __restrict__ out) {
    const int lane = threadIdx.x & 63;
    const int bid = blockIdx.x;
    if (bid < ROW_BLOCKS) {
        const int r = bid * 4 + (threadIdx.x >> 6);
        if (r >= VV) return;
        int c = cursor[r];
        if (c == 0) return;
        if (c > CAP) c = CAP;
        const float4* e4 = (const float4*)(emb + (size_t)r * EE);
        const float4 E0 = e4[lane * 2], E1 = e4[lane * 2 + 1], E2 = e4[128 + lane];
        const int l8 = lane * 8, l4 = 512 + lane * 4;
        const int base = r * CAP;
        for (int o = 0; o < c; o += 4) {
            const int nn = c - o;  // wave-uniform
            int idxv[4]; bf16x8 c8[4]; ushort4 c4v[4];
#pragma unroll
            for (int j = 0; j < 4; ++j) {
                const int jj = (j < nn) ? j : 0;
                const int idx = perm2[base + o + jj];
                idxv[j] = idx;
                const unsigned short* lrow = lmn + (size_t)(idx >> 6) * EE;
                c8[j] = *(const bf16x8*)(lrow + l8);
                c4v[j] = *(const ushort4*)(lrow + l4);
            }
            float d[4];
#pragma unroll
            for (int j = 0; j < 4; ++j) {
                d[j] = bf2f((unsigned short)c8[j][0]) * E0.x
                     + bf2f((unsigned short)c8[j][1]) * E0.y
                     + bf2f((unsigned short)c8[j][2]) * E0.z
                     + bf2f((unsigned short)c8[j][3]) * E0.w
                     + bf2f((unsigned short)c8[j][4]) * E1.x
                     + bf2f((unsigned short)c8[j][5]) * E1.y
                     + bf2f((unsigned short)c8[j][6]) * E1.z
                     + bf2f((unsigned short)c8[j][7]) * E1.w
                     + bf2f(c4v[j].x) * E2.x + bf2f(c4v[j].y) * E2.y
                     + bf2f(c4v[j].z) * E2.z + bf2f(c4v[j].w) * E2.w;
            }
#pragma unroll
            for (int m2 = 32; m2; m2 >>= 1) {
#pragma unroll
                for (int j = 0; j < 4; ++j) d[j] += __shfl_xor(d[j], m2);
            }
            if (lane == 0) {
#pragma unroll
                for (int j = 0; j < 4; ++j)
                    if (j < nn) out[idxv[j]] = d[j];
            }
        }
    } else {
        // overflow entries (rare; usually zero)
        const int nov0 = cursor[VV];
        const int nov = nov0 < OVF_CAP ? nov0 : OVF_CAP;
        const int wid = (bid - ROW_BLOCKS) * 4 + (threadIdx.x >> 6);
        const int l8 = lane * 8, l4 = 512 + lane * 4;
        for (int j = wid; j < nov; j += OVF_BLOCKS * 4) {
            const int idx = ovf[j];
            const int r = cand[idx];
            const float4* e4 = (const float4*)(emb + (size_t)r * EE);
            const float4 E0 = e4[lane * 2], E1 = e4[lane * 2 + 1], E2 = e4[128 + lane];
            const unsigned short* lrow = lmn + (size_t)(idx >> 6) * EE;
            const bf16x8 c8 = *(const bf16x8*)(lrow + l8);
            const ushort4 c4v = *(const ushort4*)(lrow + l4);
            float d = bf2f((unsigned short)c8[0]) * E0.x + bf2f((unsigned short)c8[1]) * E0.y
                    + bf2f((unsigned short)c8[2]) * E0.z + bf2f((unsigned short)c8[3]) * E0.w
                    + bf2f((unsigned short)c8[4]) * E1.x + bf2f((unsigned short)c8[5]) * E1.y
                    + bf2f((unsigned short)c8[6]) * E1.z + bf2f((unsigned short)c8[7]) * E1.w
                    + bf2f(c4v.x) * E2.x + bf2f(c4v.y) * E2.y
                    + bf2f(c4v.z) * E2.z + bf2f(c4v.w) * E2.w;
#pragma unroll
            for (int m2 = 32; m2; m2 >>= 1) d += __shfl_xor(d, m2);
            if (lane == 0) out[idx] = d;
        }
    }
}

extern "C" void kernel_launch(void* const* d_in, const int* in_sizes, int n_in,
                              void* d_out, int out_size, void* d_ws, size_t ws_size,
                              hipStream_t stream) {
    const float* seq   = (const float*)d_in[0];
    const int*   mpos  = (const int*)d_in[1];
    const int*   cand  = (const int*)d_in[2];
    const float* emb   = (const float*)d_in[3];
    const float* W     = (const float*)d_in[4];
    const float* bias  = (const float*)d_in[5];
    const float* gamma = (const float*)d_in[6];
    const float* beta  = (const float*)d_in[7];
    float* out = (float*)d_out;

    char* ws = (char*)d_ws;
    unsigned short* Wt   = (unsigned short*)(ws + OFF_WT);
    unsigned short* Ag   = (unsigned short*)(ws + OFF_AG);
    float*          lm   = (float*)(ws + OFF_LM);
    unsigned short* lmn  = (unsigned short*)(ws + OFF_LMN);
    int*            cur  = (int*)(ws + OFF_CUR);
    int*            perm2= (int*)(ws + OFF_PERM2);
    int*            ovf  = (int*)(ws + OFF_OVF);

    prep_kernel<<<WT_BLOCKS + AG_BLOCKS + ZR_BLOCKS, 256, 0, stream>>>(
        W, Wt, seq, mpos, Ag, cur);
    gemm_scatter_kernel<<<GEMM_BLOCKS + SC_BLOCKS, 256, 0, stream>>>(
        Ag, Wt, lm, cand, cur, perm2, ovf);
    ln_kernel<<<MM / 4, 256, 0, stream>>>(lm, bias, gamma, beta, lmn);
    group_logits_kernel<<<ROW_BLOCKS + OVF_BLOCKS, 256, 0, stream>>>(
        emb, lmn, cur, perm2, ovf, cand, out);
}